// Round 1
// 4644.163 us; speedup vs baseline: 1.4479x; 1.4479x over previous
//
#include <hip/hip_runtime.h>
#include <cstdint>
#include <cstddef>

// Sizes (hardcoded per reference)
static constexpr int H     = 512;    // hidden
static constexpr int WD    = 1024;   // word dim
static constexpr int NV    = 30000;  // vocab
static constexpr int NB    = 64;     // batch
static constexpr int NS    = 256;    // encoder seq len
static constexpr int NSTEP = 27;     // T-1 decode steps
static constexpr int G4    = 2048;   // 4*H
static constexpr int NVT   = 1875;   // v-tiles of 16 (16*1875 = 30000)
static constexpr int PSTR  = 16;     // u64 stride per batch for argmax slots (128B line pad)

typedef __attribute__((ext_vector_type(8))) short  bf16x8;
typedef __attribute__((ext_vector_type(4))) float  f32x4;

// float -> order-preserving uint key
__device__ __forceinline__ unsigned fkey(float f) {
  unsigned u = __float_as_uint(f);
  return u ^ (0x80000000u | (unsigned)((int)u >> 31));
}

// round-to-nearest-even fp32 -> bf16 bits
__device__ __forceinline__ unsigned short bf16rne(float f) {
  unsigned u = __float_as_uint(f);
  return (unsigned short)((u + 0x7FFFu + ((u >> 16) & 1u)) >> 16);
}

// ---------------------------------------------------------------------------
// Kernel A: u_e = W1[:H] @ W2 @ W3 @ Wv   (attention MLP collapsed to a vector;
// biases + h-term cancel in softmax over s). One block, 512 threads.
// ---------------------------------------------------------------------------
__global__ __launch_bounds__(512) void k_ue(
    const float* __restrict__ W1, const float* __restrict__ W2,
    const float* __restrict__ W3, const float* __restrict__ Wv,
    float* __restrict__ ue) {
  __shared__ float wv[H], t1[H], t2[H];
  const int tid = threadIdx.x;
  wv[tid] = Wv[tid];
  __syncthreads();
  {
    const float4* row = (const float4*)(W3 + (size_t)tid * H);
    float a = 0.f;
#pragma unroll 4
    for (int j = 0; j < H / 4; ++j) {
      float4 w = row[j];
      a += w.x * wv[4 * j] + w.y * wv[4 * j + 1] + w.z * wv[4 * j + 2] + w.w * wv[4 * j + 3];
    }
    t1[tid] = a;
  }
  __syncthreads();
  {
    const float4* row = (const float4*)(W2 + (size_t)tid * H);
    float a = 0.f;
#pragma unroll 4
    for (int j = 0; j < H / 4; ++j) {
      float4 w = row[j];
      a += w.x * t1[4 * j] + w.y * t1[4 * j + 1] + w.z * t1[4 * j + 2] + w.w * t1[4 * j + 3];
    }
    t2[tid] = a;
  }
  __syncthreads();
  {
    const float4* row = (const float4*)(W1 + (size_t)tid * H);  // rows 0..511 = enc part
    float a = 0.f;
#pragma unroll 4
    for (int j = 0; j < H / 4; ++j) {
      float4 w = row[j];
      a += w.x * t2[4 * j] + w.y * t2[4 * j + 1] + w.z * t2[4 * j + 2] + w.w * t2[4 * j + 3];
    }
    ue[tid] = a;
  }
}

// ---------------------------------------------------------------------------
// Kernel B: per batch b: score[s] = enc[b,s,:]·u_e ; aw = softmax_s(score);
// ctx[b,:] = sum_s aw[s]*enc[b,s,:].  Time-invariant. 64 blocks x 256 threads.
// ---------------------------------------------------------------------------
__global__ __launch_bounds__(256) void k_attn(
    const float* __restrict__ enc, const float* __restrict__ ue,
    float* __restrict__ ctx) {
  __shared__ float uel[H];
  __shared__ float sc[NS];
  __shared__ float red[NS];
  const int b = blockIdx.x;
  const int tid = threadIdx.x;
  uel[tid] = ue[tid];
  uel[tid + 256] = ue[tid + 256];
  __syncthreads();
  float acc = 0.f;
  {
    const float4* row = (const float4*)(enc + ((size_t)b * NS + tid) * H);
#pragma unroll 4
    for (int j = 0; j < H / 4; ++j) {
      float4 e = row[j];
      acc += e.x * uel[4 * j] + e.y * uel[4 * j + 1] + e.z * uel[4 * j + 2] + e.w * uel[4 * j + 3];
    }
  }
  red[tid] = acc;
  __syncthreads();
  for (int s = 128; s > 0; s >>= 1) {
    if (tid < s) red[tid] = fmaxf(red[tid], red[tid + s]);
    __syncthreads();
  }
  const float mx = red[0];
  __syncthreads();
  const float ex = expf(acc - mx);
  red[tid] = ex;
  __syncthreads();
  for (int s = 128; s > 0; s >>= 1) {
    if (tid < s) red[tid] += red[tid + s];
    __syncthreads();
  }
  const float inv = 1.f / red[0];
  sc[tid] = ex * inv;
  __syncthreads();
  for (int h0 = 0; h0 < H; h0 += 256) {
    const int hh = h0 + tid;
    float a = 0.f;
    for (int s = 0; s < NS; ++s) a += sc[s] * enc[((size_t)b * NS + s) * H + hh];
    ctx[b * H + hh] = a;
  }
}

// ---------------------------------------------------------------------------
// Kernel B2: gctx[b,k] = bih[k]+bhh[k] + sum_j ctx[b,j]*Wih[WD+j, k]
// (time-invariant part of the LSTM pre-activation). 64 blocks x 256 threads.
// ---------------------------------------------------------------------------
__global__ __launch_bounds__(256) void k_gctx(
    const float* __restrict__ Wih, const float* __restrict__ bih,
    const float* __restrict__ bhh, const float* __restrict__ ctx,
    float* __restrict__ gctx) {
  __shared__ float cl[8 * H];
  const int tid = threadIdx.x;
  const int kx = blockIdx.x & 7, bg = blockIdx.x >> 3;
  const int k = kx * 256 + tid;
  for (int i = tid; i < 8 * H; i += 256) cl[i] = ctx[(size_t)bg * 8 * H + i];
  __syncthreads();
  float acc[8];
  const float bias = bih[k] + bhh[k];
#pragma unroll
  for (int r = 0; r < 8; ++r) acc[r] = bias;
  const float* wp = Wih + (size_t)WD * G4 + k;
  for (int j = 0; j < H; ++j) {
    float w = wp[(size_t)j * G4];
#pragma unroll
    for (int r = 0; r < 8; ++r) acc[r] += cl[r * H + j] * w;
  }
#pragma unroll
  for (int r = 0; r < 8; ++r) gctx[(size_t)(bg * 8 + r) * G4 + k] = acc[r];
}

// ---------------------------------------------------------------------------
// Kernel W-conv (once): split Wout fp32 [512][30000] into bf16 hi/lo stored in
// MFMA-B-fragment-major layout. frag = vt*16+kt; lane l of a frag holds
// B[k = kt*32 + (l>>4)*8 + e][v = vt*16 + (l&15)], e=0..7, stored contiguously
// at (frag*64 + lane)*8. Grid: 1.92M threads = 7500 x 256.
// ---------------------------------------------------------------------------
typedef __attribute__((ext_vector_type(8))) unsigned short u16x8;

__global__ __launch_bounds__(256) void k_convW(
    const float* __restrict__ Wout, unsigned short* __restrict__ whi,
    unsigned short* __restrict__ wlo) {
  const int gid = blockIdx.x * 256 + threadIdx.x;   // 0 .. 1,920,000-1
  const int frag = gid >> 6, lane = gid & 63;
  const int vt = frag >> 4, kt = frag & 15;
  const int v  = vt * 16 + (lane & 15);
  const int k0 = kt * 32 + (lane >> 4) * 8;
  u16x8 hv, lv;
#pragma unroll
  for (int e = 0; e < 8; ++e) {
    float x = Wout[(size_t)(k0 + e) * NV + v];
    unsigned short hb = bf16rne(x);
    float hf = __uint_as_float((unsigned)hb << 16);
    hv[e] = hb;
    lv[e] = bf16rne(x - hf);
  }
  *(u16x8*)(whi + (size_t)gid * 8) = hv;
  *(u16x8*)(wlo + (size_t)gid * 8) = lv;
}

// ---------------------------------------------------------------------------
// Kernel C (per step): gates = [emb[ciw]]@Wih_top + h@Whh + gctx, LSTM pointwise.
// 256 blocks (i-strips of 2) x 256 threads. Block 0 also zeroes packed[t] and
// writes prediction t-1 (fp32) to d_out. Epilogue additionally emits the
// bf16 hi/lo MFMA-A-fragments of h for this step's logits kernel.
// ---------------------------------------------------------------------------
__global__ __launch_bounds__(256) void k_step(
    const float* __restrict__ emb, const float* __restrict__ Wih,
    const float* __restrict__ Whh, const float* __restrict__ gctx,
    const float* __restrict__ hin, float* __restrict__ hout,
    float* __restrict__ cbuf,
    const unsigned long long* __restrict__ packedPrev,
    unsigned long long* __restrict__ packedCur,
    float* __restrict__ pred,
    unsigned short* __restrict__ hfhi, unsigned short* __restrict__ hflo,
    int step) {
  __shared__ float Xt[128 * 64];   // [jj][b]
  __shared__ float4 ps4[256];
  const int tid = threadIdx.x;
  const int b = tid & 63;
  const int q = tid >> 6;          // 0..3
  const int il = q & 1, jh = q >> 1;
  const int i = blockIdx.x * 2 + il;

  int ciw = 1;  // <BOS> at step 0
  if (step > 0) {
    unsigned long long kp = packedPrev[b * PSTR];
    ciw = 0x7FFFFFFF - (int)(unsigned)(kp & 0xFFFFFFFFull);
  }
  if (blockIdx.x == 0 && tid < NB) {
    packedCur[tid * PSTR] = 0ull;  // init argmax accumulator for this step
    if (step > 0) {
      unsigned long long kp = packedPrev[tid * PSTR];
      int v = 0x7FFFFFFF - (int)(unsigned)(kp & 0xFFFFFFFFull);
      pred[tid * NSTEP + (step - 1)] = (float)v;
    }
  }
  const float* __restrict__ embrow = emb + (size_t)ciw * WD;
  float a0 = 0.f, a1 = 0.f, a2 = 0.f, a3 = 0.f;

  for (int tile = 0; tile < 12; ++tile) {
    const int jbase = tile * 128;
    __syncthreads();
    if (jbase < WD) {  // embedding part (tiles 0..7)
#pragma unroll
      for (int k = 0; k < 32; ++k) {
        int jj = k * 4 + q;
        Xt[jj * 64 + b] = embrow[jbase + jj];
      }
    } else {           // hidden-state part (tiles 8..11)
#pragma unroll
      for (int k = 0; k < 32; ++k) {
        int jj = k * 4 + q;
        Xt[jj * 64 + b] = hin[b * H + (jbase - WD + jj)];
      }
    }
    __syncthreads();
    const float* wr = ((jbase < WD) ? (Wih + (size_t)(jbase + jh * 64) * G4)
                                    : (Whh + (size_t)(jbase - WD + jh * 64) * G4)) + i;
    const float* xp = &Xt[(jh * 64) * 64 + b];
#pragma unroll 4
    for (int jj = 0; jj < 64; ++jj) {
      float x = xp[jj * 64];
      a0 += x * wr[0];
      a1 += x * wr[512];
      a2 += x * wr[1024];
      a3 += x * wr[1536];
      wr += G4;
    }
  }
  ps4[tid] = make_float4(a0, a1, a2, a3);
  __syncthreads();
  if (tid < 128) {  // jh==0 threads own (b, i): combine halves + LSTM update
    float4 m = ps4[tid];
    float4 o = ps4[tid + 128];
    const float* gb = gctx + (size_t)b * G4 + i;
    float gi = m.x + o.x + gb[0];
    float gf = m.y + o.y + gb[512];
    float gg = m.z + o.z + gb[1024];
    float go = m.w + o.w + gb[1536];
    float cp = (step == 0) ? 0.f : cbuf[b * H + i];
    float si = 1.f / (1.f + expf(-gi));
    float sf = 1.f / (1.f + expf(-gf));
    float so = 1.f / (1.f + expf(-go));
    float cn = sf * cp + si * tanhf(gg);
    float hn = so * tanhf(cn);
    cbuf[b * H + i] = cn;
    hout[b * H + i] = hn;
    // --- emit bf16 hi/lo A-fragment element for k_logits_mfma ---
    unsigned short hb = bf16rne(hn);
    float hf = __uint_as_float((unsigned)hb << 16);
    unsigned short lb = bf16rne(hn - hf);
    const int mt2 = b >> 4, kt2 = i >> 5;
    const int lane2 = (b & 15) | (((i >> 3) & 3) << 4);
    const int e2 = i & 7;
    const size_t fidx = (((size_t)(mt2 * 16 + kt2) * 64) + lane2) * 8 + e2;
    hfhi[fidx] = hb;
    hflo[fidx] = lb;
  }
}

// ---------------------------------------------------------------------------
// Kernel D (per step): logits = h @ Wout + bout via split-bf16 MFMA.
// logits ≈ hi(h)·hi(W) + lo(h)·hi(W) + hi(h)·lo(W), fp32 accumulate
// (dropped lo·lo term ~2^-17 relative). No LDS. Block = 4 waves; wave w owns
// m-tile w (16 batches), holds its full A (hi+lo, 128 VGPRs) in registers and
// streams 4 v-tiles of B fragments (shared across the block's waves via L1).
// Argmax: running best in regs, shfl_xor over 16 v-lanes, one padded atomicMax
// per (wave, b). Grid: 469 blocks x 256 threads.
// ---------------------------------------------------------------------------
__global__ __launch_bounds__(256) void k_logits_mfma(
    const unsigned short* __restrict__ whi, const unsigned short* __restrict__ wlo,
    const unsigned short* __restrict__ hfhi, const unsigned short* __restrict__ hflo,
    const float* __restrict__ bout, float* __restrict__ outSeq,
    unsigned long long* __restrict__ packedCur, int step) {
  const int tid  = threadIdx.x;
  const int lane = tid & 63;
  const int mt   = tid >> 6;            // wave id = m-tile (16 batches)
  const int vt0  = blockIdx.x * 4;
  const int vlane = lane & 15, rgrp = lane >> 4;

  // Preload this wave's full A (hi+lo) fragments: 16 kt x 2 x 4 VGPRs.
  bf16x8 ahi[16], alo[16];
  {
    const bf16x8* hh = (const bf16x8*)hfhi + (size_t)mt * 16 * 64 + lane;
    const bf16x8* hl = (const bf16x8*)hflo + (size_t)mt * 16 * 64 + lane;
#pragma unroll
    for (int kt = 0; kt < 16; ++kt) {
      ahi[kt] = hh[kt * 64];
      alo[kt] = hl[kt * 64];
    }
  }

  unsigned long long bestk[4] = {0ull, 0ull, 0ull, 0ull};

  for (int vv = 0; vv < 4; ++vv) {
    const int vt = vt0 + vv;
    if (vt >= NVT) break;               // wave-uniform
    f32x4 acc = {0.f, 0.f, 0.f, 0.f};
    const bf16x8* wh = (const bf16x8*)whi + (size_t)vt * 16 * 64 + lane;
    const bf16x8* wl = (const bf16x8*)wlo + (size_t)vt * 16 * 64 + lane;
#pragma unroll
    for (int kt = 0; kt < 16; ++kt) {
      bf16x8 bh = wh[kt * 64];
      bf16x8 bl = wl[kt * 64];
      acc = __builtin_amdgcn_mfma_f32_16x16x32_bf16(ahi[kt], bh, acc, 0, 0, 0);
      acc = __builtin_amdgcn_mfma_f32_16x16x32_bf16(alo[kt], bh, acc, 0, 0, 0);
      acc = __builtin_amdgcn_mfma_f32_16x16x32_bf16(ahi[kt], bl, acc, 0, 0, 0);
    }
    const int v = vt * 16 + vlane;
    const float bo = bout[v];
    const int bbase = mt * 16 + rgrp * 4;
    float* op = outSeq + ((size_t)bbase * NSTEP + step) * NV + v;
#pragma unroll
    for (int r = 0; r < 4; ++r) {
      float val = acc[r] + bo;
      op[(size_t)r * NSTEP * NV] = val;
      unsigned long long key = ((unsigned long long)fkey(val) << 32)
                             | (unsigned long long)(0x7FFFFFFFu - (unsigned)v);
      if (key > bestk[r]) bestk[r] = key;
    }
  }

  // reduce over the 16 v-lanes (xor masks <16 stay within the rgrp group)
#pragma unroll
  for (int m = 8; m >= 1; m >>= 1) {
#pragma unroll
    for (int r = 0; r < 4; ++r) {
      unsigned long long o = __shfl_xor(bestk[r], m, 64);
      if (o > bestk[r]) bestk[r] = o;
    }
  }
  if (vlane == 0) {
#pragma unroll
    for (int r = 0; r < 4; ++r)
      atomicMax(&packedCur[(mt * 16 + rgrp * 4 + r) * PSTR], bestk[r]);
  }
}

// Final prediction (step 26) from last packed argmax.
__global__ void k_predfinal(const unsigned long long* __restrict__ packed,
                            float* __restrict__ pred) {
  const int b = threadIdx.x;
  int v = 0x7FFFFFFF - (int)(unsigned)(packed[b * PSTR] & 0xFFFFFFFFull);
  pred[b * NSTEP + (NSTEP - 1)] = (float)v;
}

// ---------------------------------------------------------------------------
extern "C" void kernel_launch(void* const* d_in, const int* in_sizes, int n_in,
                              void* d_out, int out_size, void* d_ws, size_t ws_size,
                              hipStream_t stream) {
  (void)in_sizes; (void)n_in; (void)out_size; (void)ws_size;
  const float* encLast = (const float*)d_in[0];   // (1,B,H)
  const float* enc     = (const float*)d_in[1];   // (B,S,H)
  const float* emb     = (const float*)d_in[4];   // (V,WD)
  const float* W1      = (const float*)d_in[5];
  const float* W2      = (const float*)d_in[7];
  const float* W3      = (const float*)d_in[9];
  const float* Wv      = (const float*)d_in[11];
  const float* Wih     = (const float*)d_in[12];  // (1536,2048)
  const float* Whh     = (const float*)d_in[13];  // (512,2048)
  const float* bih     = (const float*)d_in[14];
  const float* bhh     = (const float*)d_in[15];
  const float* Wout    = (const float*)d_in[16];  // (512,30000)
  const float* bout    = (const float*)d_in[17];
  // b1/b2/b3 (d_in[6,8,10]) cancel in softmax; targets/tr_steps unused.

  float* wsf = (float*)d_ws;
  float* ue   = wsf;                 // 512
  float* ctx  = wsf + 512;           // 64*512
  float* gctx = wsf + 33280;         // 64*2048
  float* hb0  = wsf + 164352;        // 64*512
  float* hb1  = wsf + 197120;        // 64*512
  float* cbuf = wsf + 229888;        // 64*512
  unsigned long long* packedP = (unsigned long long*)(wsf + 262656); // 27*64*PSTR u64
  unsigned short* hfhi = (unsigned short*)(wsf + 317952);  // 32768 bf16
  unsigned short* hflo = (unsigned short*)(wsf + 334336);  // 32768 bf16
  unsigned short* whi  = (unsigned short*)(wsf + 350720);  // 15.36M bf16
  unsigned short* wlo  = (unsigned short*)(wsf + 8030720); // 15.36M bf16 (ws ends ~62.9 MB)

  float* outSeq = (float*)d_out;                        // fp32 seq [B,27,V]
  float* pred   = outSeq + (size_t)NB * NSTEP * NV;     // fp32 preds [B,27]

  k_ue   <<<1, 512, 0, stream>>>(W1, W2, W3, Wv, ue);
  k_attn <<<NB, 256, 0, stream>>>(enc, ue, ctx);
  k_gctx <<<64, 256, 0, stream>>>(Wih, bih, bhh, ctx, gctx);
  k_convW<<<7500, 256, 0, stream>>>(Wout, whi, wlo);    // 1875*16*64 threads

  for (int t = 0; t < NSTEP; ++t) {
    const float* hin = (t == 0) ? encLast : ((t & 1) ? hb0 : hb1);
    float* hout = (t & 1) ? hb1 : hb0;
    const unsigned long long* pprev = packedP + (t > 0 ? (size_t)(t - 1) * NB * PSTR : 0);
    unsigned long long* pcur = packedP + (size_t)t * NB * PSTR;
    k_step<<<256, 256, 0, stream>>>(emb, Wih, Whh, gctx, hin, hout, cbuf,
                                    pprev, pcur, pred, hfhi, hflo, t);
    k_logits_mfma<<<469, 256, 0, stream>>>(whi, wlo, hfhi, hflo, bout, outSeq,
                                           pcur, t);
  }
  k_predfinal<<<1, NB, 0, stream>>>(packedP + (size_t)(NSTEP - 1) * NB * PSTR, pred);
}

// Round 3
// 2064.789 us; speedup vs baseline: 3.2567x; 2.2492x over previous
//
#include <hip/hip_runtime.h>
#include <cstdint>
#include <cstddef>

// Sizes (hardcoded per reference)
static constexpr int H     = 512;    // hidden
static constexpr int WD    = 1024;   // word dim
static constexpr int NV    = 30000;  // vocab
static constexpr int NB    = 64;     // batch
static constexpr int NS    = 256;    // encoder seq len
static constexpr int NSTEP = 27;     // T-1 decode steps
static constexpr int G4    = 2048;   // 4*H
static constexpr int NVT   = 1875;   // v-tiles of 16 (16*1875 = 30000)
static constexpr int PSTR  = 16;     // u64 stride per batch for argmax slots (128B line pad)
static constexpr int NKT   = 48;     // k-tiles of 32 in gate GEMM (K = 1536)

typedef __attribute__((ext_vector_type(8))) short  bf16x8;
typedef __attribute__((ext_vector_type(4))) float  f32x4;
typedef __attribute__((ext_vector_type(8))) unsigned short u16x8;

// float -> order-preserving uint key
__device__ __forceinline__ unsigned fkey(float f) {
  unsigned u = __float_as_uint(f);
  return u ^ (0x80000000u | (unsigned)((int)u >> 31));
}

// round-to-nearest-even fp32 -> bf16 bits
__device__ __forceinline__ unsigned short bf16rne(float f) {
  unsigned u = __float_as_uint(f);
  return (unsigned short)((u + 0x7FFFu + ((u >> 16) & 1u)) >> 16);
}

// ---------------------------------------------------------------------------
// Kernel A: u_e = W1[:H] @ W2 @ W3 @ Wv   (attention MLP collapsed to a vector;
// biases + h-term cancel in softmax over s). One block, 512 threads.
// ---------------------------------------------------------------------------
__global__ __launch_bounds__(512) void k_ue(
    const float* __restrict__ W1, const float* __restrict__ W2,
    const float* __restrict__ W3, const float* __restrict__ Wv,
    float* __restrict__ ue) {
  __shared__ float wv[H], t1[H], t2[H];
  const int tid = threadIdx.x;
  wv[tid] = Wv[tid];
  __syncthreads();
  {
    const float4* row = (const float4*)(W3 + (size_t)tid * H);
    float a = 0.f;
#pragma unroll 4
    for (int j = 0; j < H / 4; ++j) {
      float4 w = row[j];
      a += w.x * wv[4 * j] + w.y * wv[4 * j + 1] + w.z * wv[4 * j + 2] + w.w * wv[4 * j + 3];
    }
    t1[tid] = a;
  }
  __syncthreads();
  {
    const float4* row = (const float4*)(W2 + (size_t)tid * H);
    float a = 0.f;
#pragma unroll 4
    for (int j = 0; j < H / 4; ++j) {
      float4 w = row[j];
      a += w.x * t1[4 * j] + w.y * t1[4 * j + 1] + w.z * t1[4 * j + 2] + w.w * t1[4 * j + 3];
    }
    t2[tid] = a;
  }
  __syncthreads();
  {
    const float4* row = (const float4*)(W1 + (size_t)tid * H);  // rows 0..511 = enc part
    float a = 0.f;
#pragma unroll 4
    for (int j = 0; j < H / 4; ++j) {
      float4 w = row[j];
      a += w.x * t2[4 * j] + w.y * t2[4 * j + 1] + w.z * t2[4 * j + 2] + w.w * t2[4 * j + 3];
    }
    ue[tid] = a;
  }
}

// ---------------------------------------------------------------------------
// Kernel B: per batch b: score[s] = enc[b,s,:]·u_e ; aw = softmax_s(score);
// ctx[b,:] = sum_s aw[s]*enc[b,s,:].  Time-invariant. 64 blocks x 256 threads.
// ---------------------------------------------------------------------------
__global__ __launch_bounds__(256) void k_attn(
    const float* __restrict__ enc, const float* __restrict__ ue,
    float* __restrict__ ctx) {
  __shared__ float uel[H];
  __shared__ float sc[NS];
  __shared__ float red[NS];
  const int b = blockIdx.x;
  const int tid = threadIdx.x;
  uel[tid] = ue[tid];
  uel[tid + 256] = ue[tid + 256];
  __syncthreads();
  float acc = 0.f;
  {
    const float4* row = (const float4*)(enc + ((size_t)b * NS + tid) * H);
#pragma unroll 4
    for (int j = 0; j < H / 4; ++j) {
      float4 e = row[j];
      acc += e.x * uel[4 * j] + e.y * uel[4 * j + 1] + e.z * uel[4 * j + 2] + e.w * uel[4 * j + 3];
    }
  }
  red[tid] = acc;
  __syncthreads();
  for (int s = 128; s > 0; s >>= 1) {
    if (tid < s) red[tid] = fmaxf(red[tid], red[tid + s]);
    __syncthreads();
  }
  const float mx = red[0];
  __syncthreads();
  const float ex = expf(acc - mx);
  red[tid] = ex;
  __syncthreads();
  for (int s = 128; s > 0; s >>= 1) {
    if (tid < s) red[tid] += red[tid + s];
    __syncthreads();
  }
  const float inv = 1.f / red[0];
  sc[tid] = ex * inv;
  __syncthreads();
  for (int h0 = 0; h0 < H; h0 += 256) {
    const int hh = h0 + tid;
    float a = 0.f;
    for (int s = 0; s < NS; ++s) a += sc[s] * enc[((size_t)b * NS + s) * H + hh];
    ctx[b * H + hh] = a;
  }
}

// ---------------------------------------------------------------------------
// Kernel B2: gctx[b,k] = bih[k]+bhh[k] + sum_j ctx[b,j]*Wih[WD+j, k]
// (time-invariant part of the LSTM pre-activation). 64 blocks x 256 threads.
// ---------------------------------------------------------------------------
__global__ __launch_bounds__(256) void k_gctx(
    const float* __restrict__ Wih, const float* __restrict__ bih,
    const float* __restrict__ bhh, const float* __restrict__ ctx,
    float* __restrict__ gctx) {
  __shared__ float cl[8 * H];
  const int tid = threadIdx.x;
  const int kx = blockIdx.x & 7, bg = blockIdx.x >> 3;
  const int k = kx * 256 + tid;
  for (int i = tid; i < 8 * H; i += 256) cl[i] = ctx[(size_t)bg * 8 * H + i];
  __syncthreads();
  float acc[8];
  const float bias = bih[k] + bhh[k];
#pragma unroll
  for (int r = 0; r < 8; ++r) acc[r] = bias;
  const float* wp = Wih + (size_t)WD * G4 + k;
  for (int j = 0; j < H; ++j) {
    float w = wp[(size_t)j * G4];
#pragma unroll
    for (int r = 0; r < 8; ++r) acc[r] += cl[r * H + j] * w;
  }
#pragma unroll
  for (int r = 0; r < 8; ++r) gctx[(size_t)(bg * 8 + r) * G4 + k] = acc[r];
}

// ---------------------------------------------------------------------------
// Kernel W-conv (once): split Wout fp32 [512][30000] into bf16 hi/lo stored in
// MFMA-B-fragment-major layout. frag = vt*16+kt; lane l of a frag holds
// B[k = kt*32 + (l>>4)*8 + e][v = vt*16 + (l&15)], e=0..7, stored contiguously
// at (frag*64 + lane)*8. Grid: 1.92M threads = 7500 x 256.
// ---------------------------------------------------------------------------
__global__ __launch_bounds__(256) void k_convW(
    const float* __restrict__ Wout, unsigned short* __restrict__ whi,
    unsigned short* __restrict__ wlo) {
  const int gid = blockIdx.x * 256 + threadIdx.x;   // 0 .. 1,920,000-1
  const int frag = gid >> 6, lane = gid & 63;
  const int vt = frag >> 4, kt = frag & 15;
  const int v  = vt * 16 + (lane & 15);
  const int k0 = kt * 32 + (lane >> 4) * 8;
  u16x8 hv, lv;
#pragma unroll
  for (int e = 0; e < 8; ++e) {
    float x = Wout[(size_t)(k0 + e) * NV + v];
    unsigned short hb = bf16rne(x);
    float hf = __uint_as_float((unsigned)hb << 16);
    hv[e] = hb;
    lv[e] = bf16rne(x - hf);
  }
  *(u16x8*)(whi + (size_t)gid * 8) = hv;
  *(u16x8*)(wlo + (size_t)gid * 8) = lv;
}

// ---------------------------------------------------------------------------
// Kernel W2-conv (once): split the stacked gate weight [Wih_top(1024); Whh(512)]
// fp32 [1536][2048] into bf16 hi/lo fragment-major. frag = vt*48 + kt
// (vt = 0..127, kt = 0..47); lane l holds W[k = kt*32+(l>>4)*8+e][n = vt*16+(l&15)].
// Grid: 128*48*64 = 393216 threads = 1536 x 256.
// ---------------------------------------------------------------------------
__global__ __launch_bounds__(256) void k_convW2(
    const float* __restrict__ Wih, const float* __restrict__ Whh,
    unsigned short* __restrict__ whi2, unsigned short* __restrict__ wlo2) {
  const int gid = blockIdx.x * 256 + threadIdx.x;
  const int frag = gid >> 6, lane = gid & 63;
  const int vt = frag / NKT, kt = frag % NKT;
  const int n  = vt * 16 + (lane & 15);
  const int k0 = kt * 32 + (lane >> 4) * 8;
  u16x8 hv, lv;
#pragma unroll
  for (int e = 0; e < 8; ++e) {
    int k = k0 + e;
    float x = (k < WD) ? Wih[(size_t)k * G4 + n] : Whh[(size_t)(k - WD) * G4 + n];
    unsigned short hb = bf16rne(x);
    float hf = __uint_as_float((unsigned)hb << 16);
    hv[e] = hb;
    lv[e] = bf16rne(x - hf);
  }
  *(u16x8*)(whi2 + (size_t)gid * 8) = hv;
  *(u16x8*)(wlo2 + (size_t)gid * 8) = lv;
}

// ---------------------------------------------------------------------------
// Kernel E (per step): gather emb[ciw[b]] and convert to A-fragments of the emb
// part (kt 0..31, layout [mt][32][64][8]). At step 0 also converts h0 = encLast
// into hf0 (layout [mt][16][64][8]). Block 0 writes pred(t-1) and zeroes
// packedCur. Grid: 64 blocks (one per batch) x 128 threads.
// ---------------------------------------------------------------------------
__global__ __launch_bounds__(128) void k_emb(
    const float* __restrict__ emb, const float* __restrict__ encLast,
    const unsigned long long* __restrict__ packedPrev,
    unsigned long long* __restrict__ packedCur,
    float* __restrict__ pred,
    unsigned short* __restrict__ efhi, unsigned short* __restrict__ eflo,
    unsigned short* __restrict__ h0hi, unsigned short* __restrict__ h0lo,
    int step) {
  const int b = blockIdx.x, tid = threadIdx.x;
  int ciw = 1;  // <BOS>
  if (step > 0) {
    unsigned long long kp = packedPrev[b * PSTR];
    ciw = 0x7FFFFFFF - (int)(unsigned)(kp & 0xFFFFFFFFull);
  }
  if (b == 0 && tid < NB) {
    if (step > 0) {
      unsigned long long kp = packedPrev[tid * PSTR];
      int v = 0x7FFFFFFF - (int)(unsigned)(kp & 0xFFFFFFFFull);
      pred[tid * NSTEP + (step - 1)] = (float)v;
    }
    packedCur[tid * PSTR] = 0ull;
  }
  const int mt = b >> 4;
  const int lane = (b & 15) | ((tid & 3) << 4);
  {
    // emb part: thread handles k = tid*8 .. tid*8+7 (kt = tid>>2)
    const float* src = emb + (size_t)ciw * WD + tid * 8;
    float4 f0 = *(const float4*)src;
    float4 f1 = *(const float4*)(src + 4);
    float vals[8] = {f0.x, f0.y, f0.z, f0.w, f1.x, f1.y, f1.z, f1.w};
    u16x8 hv, lv;
#pragma unroll
    for (int e = 0; e < 8; ++e) {
      unsigned short hb = bf16rne(vals[e]);
      float hf = __uint_as_float((unsigned)hb << 16);
      hv[e] = hb;
      lv[e] = bf16rne(vals[e] - hf);
    }
    const size_t fi = ((size_t)(mt * 32 + (tid >> 2)) * 64 + lane) * 8;
    *(u16x8*)(efhi + fi) = hv;
    *(u16x8*)(eflo + fi) = lv;
  }
  if (step == 0 && tid < 64) {
    // h0 part: k = tid*8 .. +7 within H (kt = tid>>2), into hf0
    const float* src = encLast + (size_t)b * H + tid * 8;
    float4 f0 = *(const float4*)src;
    float4 f1 = *(const float4*)(src + 4);
    float vals[8] = {f0.x, f0.y, f0.z, f0.w, f1.x, f1.y, f1.z, f1.w};
    u16x8 hv, lv;
#pragma unroll
    for (int e = 0; e < 8; ++e) {
      unsigned short hb = bf16rne(vals[e]);
      float hf = __uint_as_float((unsigned)hb << 16);
      hv[e] = hb;
      lv[e] = bf16rne(vals[e] - hf);
    }
    const size_t fi = ((size_t)(mt * 16 + (tid >> 2)) * 64 + lane) * 8;
    *(u16x8*)(h0hi + fi) = hv;
    *(u16x8*)(h0lo + fi) = lv;
  }
}

// ---------------------------------------------------------------------------
// Kernel C (per step): gates = x @ [Wih_top;Whh] via split-bf16 MFMA + gctx,
// then fused LSTM pointwise + h -> bf16 hi/lo fragment emission (into the
// OTHER h buffer — read/write double-buffered to avoid the cross-block race).
// Grid dim3(32, 2): blockIdx.x = h-col group (16 cols), blockIdx.y = mt-pair
// (32 batches). 4 waves = 4 gates; wave g computes gate g's 16 cols for both
// m-tiles over K=1536 (2 x 48 x 3 = 288 MFMA), exchanges through LDS.
// ---------------------------------------------------------------------------
__global__ __launch_bounds__(256) void k_gates(
    const unsigned short* __restrict__ whi2, const unsigned short* __restrict__ wlo2,
    const unsigned short* __restrict__ efhi, const unsigned short* __restrict__ eflo,
    const unsigned short* __restrict__ hihi, const unsigned short* __restrict__ hilo,
    unsigned short* __restrict__ hohi, unsigned short* __restrict__ holo,
    const float* __restrict__ gctx, float* __restrict__ cbuf, int step) {
  __shared__ float gl[4][32][17];   // [gate][b_local][col] padded
  const int tid = threadIdx.x;
  const int lane = tid & 63, g = tid >> 6;
  const int x = blockIdx.x, p = blockIdx.y;
  const int vt = g * 32 + x;

  f32x4 acc0 = {0.f, 0.f, 0.f, 0.f};
  f32x4 acc1 = {0.f, 0.f, 0.f, 0.f};
  const bf16x8* wh = (const bf16x8*)whi2 + (size_t)vt * NKT * 64 + lane;
  const bf16x8* wl = (const bf16x8*)wlo2 + (size_t)vt * NKT * 64 + lane;
  const bf16x8* aeh = (const bf16x8*)efhi + (size_t)(p * 2) * 32 * 64 + lane;
  const bf16x8* ael = (const bf16x8*)eflo + (size_t)(p * 2) * 32 * 64 + lane;
  const bf16x8* ahh = (const bf16x8*)hihi + (size_t)(p * 2) * 16 * 64 + lane;
  const bf16x8* ahl = (const bf16x8*)hilo + (size_t)(p * 2) * 16 * 64 + lane;
  // emb k-tiles (kt 0..31)
#pragma unroll 4
  for (int kt = 0; kt < 32; ++kt) {
    bf16x8 bh = wh[kt * 64];
    bf16x8 bl = wl[kt * 64];
    bf16x8 a0h = aeh[kt * 64];
    bf16x8 a0l = ael[kt * 64];
    bf16x8 a1h = aeh[(32 + kt) * 64];
    bf16x8 a1l = ael[(32 + kt) * 64];
    acc0 = __builtin_amdgcn_mfma_f32_16x16x32_bf16(a0h, bh, acc0, 0, 0, 0);
    acc0 = __builtin_amdgcn_mfma_f32_16x16x32_bf16(a0l, bh, acc0, 0, 0, 0);
    acc0 = __builtin_amdgcn_mfma_f32_16x16x32_bf16(a0h, bl, acc0, 0, 0, 0);
    acc1 = __builtin_amdgcn_mfma_f32_16x16x32_bf16(a1h, bh, acc1, 0, 0, 0);
    acc1 = __builtin_amdgcn_mfma_f32_16x16x32_bf16(a1l, bh, acc1, 0, 0, 0);
    acc1 = __builtin_amdgcn_mfma_f32_16x16x32_bf16(a1h, bl, acc1, 0, 0, 0);
  }
  // h k-tiles (kt 32..47 of W, 0..15 of the h fragment buffer)
#pragma unroll 4
  for (int kt = 0; kt < 16; ++kt) {
    bf16x8 bh = wh[(32 + kt) * 64];
    bf16x8 bl = wl[(32 + kt) * 64];
    bf16x8 a0h = ahh[kt * 64];
    bf16x8 a0l = ahl[kt * 64];
    bf16x8 a1h = ahh[(16 + kt) * 64];
    bf16x8 a1l = ahl[(16 + kt) * 64];
    acc0 = __builtin_amdgcn_mfma_f32_16x16x32_bf16(a0h, bh, acc0, 0, 0, 0);
    acc0 = __builtin_amdgcn_mfma_f32_16x16x32_bf16(a0l, bh, acc0, 0, 0, 0);
    acc0 = __builtin_amdgcn_mfma_f32_16x16x32_bf16(a0h, bl, acc0, 0, 0, 0);
    acc1 = __builtin_amdgcn_mfma_f32_16x16x32_bf16(a1h, bh, acc1, 0, 0, 0);
    acc1 = __builtin_amdgcn_mfma_f32_16x16x32_bf16(a1l, bh, acc1, 0, 0, 0);
    acc1 = __builtin_amdgcn_mfma_f32_16x16x32_bf16(a1h, bl, acc1, 0, 0, 0);
  }
  {
    const int c = lane & 15, rbase = (lane >> 4) * 4;
#pragma unroll
    for (int r = 0; r < 4; ++r) {
      gl[g][rbase + r][c] = acc0[r];
      gl[g][16 + rbase + r][c] = acc1[r];
    }
  }
  __syncthreads();
  // pointwise LSTM for 512 (b,i) pairs; 2 per thread
  for (int pi = tid; pi < 512; pi += 256) {
    const int bl_ = pi >> 4, c = pi & 15;
    const int b = p * 32 + bl_;
    const int i = x * 16 + c;
    const float* gb = gctx + (size_t)b * G4 + i;
    float gi = gl[0][bl_][c] + gb[0];
    float gf = gl[1][bl_][c] + gb[512];
    float gg = gl[2][bl_][c] + gb[1024];
    float go = gl[3][bl_][c] + gb[1536];
    float cp = (step == 0) ? 0.f : cbuf[b * H + i];
    float si = 1.f / (1.f + expf(-gi));
    float sf = 1.f / (1.f + expf(-gf));
    float so = 1.f / (1.f + expf(-go));
    float cn = sf * cp + si * tanhf(gg);
    float hn = so * tanhf(cn);
    cbuf[b * H + i] = cn;
    // emit bf16 hi/lo fragment element of new h into the OUT buffer
    unsigned short hb = bf16rne(hn);
    float hf = __uint_as_float((unsigned)hb << 16);
    unsigned short lb = bf16rne(hn - hf);
    const int mt = b >> 4;
    const int kt2 = i >> 5;
    const int lane2 = (b & 15) | (((i >> 3) & 3) << 4);
    const int e2 = i & 7;
    const size_t fi = ((size_t)(mt * 16 + kt2) * 64 + lane2) * 8 + e2;
    hohi[fi] = hb;
    holo[fi] = lb;
  }
}

// ---------------------------------------------------------------------------
// Kernel D (per step): logits = h @ Wout + bout via split-bf16 MFMA.
// A-fragments read from this step's h-out buffer ([mt][16][64][8]).
// Grid: 469 blocks x 256 threads (4 waves = 4 m-tiles).
// ---------------------------------------------------------------------------
__global__ __launch_bounds__(256) void k_logits_mfma(
    const unsigned short* __restrict__ whi, const unsigned short* __restrict__ wlo,
    const unsigned short* __restrict__ hfhi, const unsigned short* __restrict__ hflo,
    const float* __restrict__ bout, float* __restrict__ outSeq,
    unsigned long long* __restrict__ packedCur, int step) {
  const int tid  = threadIdx.x;
  const int lane = tid & 63;
  const int mt   = tid >> 6;            // wave id = m-tile (16 batches)
  const int vt0  = blockIdx.x * 4;
  const int vlane = lane & 15, rgrp = lane >> 4;

  // Preload this wave's full A (hi+lo) fragments: 16 kt x 2 x 4 VGPRs.
  bf16x8 ahi[16], alo[16];
  {
    const bf16x8* hh = (const bf16x8*)hfhi + (size_t)mt * 16 * 64 + lane;
    const bf16x8* hl = (const bf16x8*)hflo + (size_t)mt * 16 * 64 + lane;
#pragma unroll
    for (int kt = 0; kt < 16; ++kt) {
      ahi[kt] = hh[kt * 64];
      alo[kt] = hl[kt * 64];
    }
  }

  unsigned long long bestk[4] = {0ull, 0ull, 0ull, 0ull};

  for (int vv = 0; vv < 4; ++vv) {
    const int vt = vt0 + vv;
    if (vt >= NVT) break;               // wave-uniform
    f32x4 acc = {0.f, 0.f, 0.f, 0.f};
    const bf16x8* wh = (const bf16x8*)whi + (size_t)vt * 16 * 64 + lane;
    const bf16x8* wl = (const bf16x8*)wlo + (size_t)vt * 16 * 64 + lane;
#pragma unroll
    for (int kt = 0; kt < 16; ++kt) {
      bf16x8 bh = wh[kt * 64];
      bf16x8 bl = wl[kt * 64];
      acc = __builtin_amdgcn_mfma_f32_16x16x32_bf16(ahi[kt], bh, acc, 0, 0, 0);
      acc = __builtin_amdgcn_mfma_f32_16x16x32_bf16(alo[kt], bh, acc, 0, 0, 0);
      acc = __builtin_amdgcn_mfma_f32_16x16x32_bf16(ahi[kt], bl, acc, 0, 0, 0);
    }
    const int v = vt * 16 + vlane;
    const float bo = bout[v];
    const int bbase = mt * 16 + rgrp * 4;
    float* op = outSeq + ((size_t)bbase * NSTEP + step) * NV + v;
#pragma unroll
    for (int r = 0; r < 4; ++r) {
      float val = acc[r] + bo;
      op[(size_t)r * NSTEP * NV] = val;
      unsigned long long key = ((unsigned long long)fkey(val) << 32)
                             | (unsigned long long)(0x7FFFFFFFu - (unsigned)v);
      if (key > bestk[r]) bestk[r] = key;
    }
  }

  // reduce over the 16 v-lanes (xor masks <16 stay within the rgrp group)
#pragma unroll
  for (int m = 8; m >= 1; m >>= 1) {
#pragma unroll
    for (int r = 0; r < 4; ++r) {
      unsigned long long o = __shfl_xor(bestk[r], m, 64);
      if (o > bestk[r]) bestk[r] = o;
    }
  }
  if (vlane == 0) {
#pragma unroll
    for (int r = 0; r < 4; ++r)
      atomicMax(&packedCur[(mt * 16 + rgrp * 4 + r) * PSTR], bestk[r]);
  }
}

// Final prediction (step 26) from last packed argmax.
__global__ void k_predfinal(const unsigned long long* __restrict__ packed,
                            float* __restrict__ pred) {
  const int b = threadIdx.x;
  int v = 0x7FFFFFFF - (int)(unsigned)(packed[b * PSTR] & 0xFFFFFFFFull);
  pred[b * NSTEP + (NSTEP - 1)] = (float)v;
}

// ---------------------------------------------------------------------------
extern "C" void kernel_launch(void* const* d_in, const int* in_sizes, int n_in,
                              void* d_out, int out_size, void* d_ws, size_t ws_size,
                              hipStream_t stream) {
  (void)in_sizes; (void)n_in; (void)out_size; (void)ws_size;
  const float* encLast = (const float*)d_in[0];   // (1,B,H)
  const float* enc     = (const float*)d_in[1];   // (B,S,H)
  const float* emb     = (const float*)d_in[4];   // (V,WD)
  const float* W1      = (const float*)d_in[5];
  const float* W2      = (const float*)d_in[7];
  const float* W3      = (const float*)d_in[9];
  const float* Wv      = (const float*)d_in[11];
  const float* Wih     = (const float*)d_in[12];  // (1536,2048)
  const float* Whh     = (const float*)d_in[13];  // (512,2048)
  const float* bih     = (const float*)d_in[14];
  const float* bhh     = (const float*)d_in[15];
  const float* Wout    = (const float*)d_in[16];  // (512,30000)
  const float* bout    = (const float*)d_in[17];
  // b1/b2/b3 (d_in[6,8,10]) cancel in softmax; targets/tr_steps unused.

  // Workspace layout (float offsets; sizes carefully non-overlapping):
  float* wsf = (float*)d_ws;
  float* ue   = wsf;                 // +512                       -> 512
  float* ctx  = wsf + 512;           // +32768                     -> 33280
  float* gctx = wsf + 33280;         // +131072                    -> 164352
  float* cbuf = wsf + 164352;        // +32768                     -> 197120
  unsigned long long* packedP = (unsigned long long*)(wsf + 197120); // 27*64*16 u64 = +55296 -> 252416
  unsigned short* efhi = (unsigned short*)(wsf + 252416);   // 65536 u16 = +32768 -> 285184
  unsigned short* eflo = (unsigned short*)(wsf + 285184);   // +32768 -> 317952
  unsigned short* h0hi = (unsigned short*)(wsf + 317952);   // 32768 u16 = +16384 -> 334336
  unsigned short* h0lo = (unsigned short*)(wsf + 334336);   // +16384 -> 350720
  unsigned short* h1hi = (unsigned short*)(wsf + 350720);   // +16384 -> 367104
  unsigned short* h1lo = (unsigned short*)(wsf + 367104);   // +16384 -> 383488
  unsigned short* whi2 = (unsigned short*)(wsf + 383488);   // 3145728 u16 = +1572864 -> 1956352
  unsigned short* wlo2 = (unsigned short*)(wsf + 1956352);  // +1572864 -> 3529216
  unsigned short* whi  = (unsigned short*)(wsf + 3529216);  // 15360000 u16 = +7680000 -> 11209216
  unsigned short* wlo  = (unsigned short*)(wsf + 11209216); // +7680000 -> 18889216 (~75.6 MB)

  float* outSeq = (float*)d_out;                        // fp32 seq [B,27,V]
  float* pred   = outSeq + (size_t)NB * NSTEP * NV;     // fp32 preds [B,27]

  k_ue    <<<1, 512, 0, stream>>>(W1, W2, W3, Wv, ue);
  k_attn  <<<NB, 256, 0, stream>>>(enc, ue, ctx);
  k_gctx  <<<64, 256, 0, stream>>>(Wih, bih, bhh, ctx, gctx);
  k_convW <<<7500, 256, 0, stream>>>(Wout, whi, wlo);
  k_convW2<<<1536, 256, 0, stream>>>(Wih, Whh, whi2, wlo2);

  for (int t = 0; t < NSTEP; ++t) {
    const unsigned long long* pprev = packedP + (t > 0 ? (size_t)(t - 1) * NB * PSTR : 0);
    unsigned long long* pcur = packedP + (size_t)t * NB * PSTR;
    // h double-buffer: even steps read hf0 / write hf1; odd steps the reverse.
    const unsigned short* hihi = (t & 1) ? h1hi : h0hi;
    const unsigned short* hilo = (t & 1) ? h1lo : h0lo;
    unsigned short* hohi = (t & 1) ? h0hi : h1hi;
    unsigned short* holo = (t & 1) ? h0lo : h1lo;
    k_emb<<<NB, 128, 0, stream>>>(emb, encLast, pprev, pcur, pred,
                                  efhi, eflo, h0hi, h0lo, t);
    k_gates<<<dim3(32, 2), 256, 0, stream>>>(whi2, wlo2, efhi, eflo,
                                             hihi, hilo, hohi, holo,
                                             gctx, cbuf, t);
    k_logits_mfma<<<469, 256, 0, stream>>>(whi, wlo, hohi, holo, bout, outSeq,
                                           pcur, t);
  }
  k_predfinal<<<1, NB, 0, stream>>>(packedP + (size_t)(NSTEP - 1) * NB * PSTR, pred);
}

// Round 4
// 1794.418 us; speedup vs baseline: 3.7473x; 1.1507x over previous
//
#include <hip/hip_runtime.h>
#include <cstdint>
#include <cstddef>

// Sizes (hardcoded per reference)
static constexpr int H     = 512;    // hidden
static constexpr int WD    = 1024;   // word dim
static constexpr int NV    = 30000;  // vocab
static constexpr int NB    = 64;     // batch
static constexpr int NS    = 256;    // encoder seq len
static constexpr int NSTEP = 27;     // T-1 decode steps
static constexpr int G4    = 2048;   // 4*H
static constexpr int NVT   = 1875;   // v-tiles of 16 (16*1875 = 30000)
static constexpr int PSTR  = 16;     // u64 stride per batch for argmax slots (128B line pad)
static constexpr int NKT   = 48;     // k-tiles of 32 in gate GEMM (K = 1536)

typedef __attribute__((ext_vector_type(8))) short  bf16x8;
typedef __attribute__((ext_vector_type(4))) float  f32x4;
typedef __attribute__((ext_vector_type(8))) unsigned short u16x8;

// float -> order-preserving uint key
__device__ __forceinline__ unsigned fkey(float f) {
  unsigned u = __float_as_uint(f);
  return u ^ (0x80000000u | (unsigned)((int)u >> 31));
}

// round-to-nearest-even fp32 -> bf16 bits
__device__ __forceinline__ unsigned short bf16rne(float f) {
  unsigned u = __float_as_uint(f);
  return (unsigned short)((u + 0x7FFFu + ((u >> 16) & 1u)) >> 16);
}

// split 8 fp32 into bf16 hi (rne) + bf16 lo (rne of residual)
__device__ __forceinline__ void split8(float4 f0, float4 f1, bf16x8& hi, bf16x8& lo) {
  float v[8] = {f0.x, f0.y, f0.z, f0.w, f1.x, f1.y, f1.z, f1.w};
#pragma unroll
  for (int e = 0; e < 8; ++e) {
    unsigned short hb = bf16rne(v[e]);
    hi[e] = (short)hb;
    lo[e] = (short)bf16rne(v[e] - __uint_as_float((unsigned)hb << 16));
  }
}

// ---------------------------------------------------------------------------
// Kernel A: u_e = W1[:H] @ W2 @ W3 @ Wv   (attention MLP collapsed to a vector;
// biases + h-term cancel in softmax over s). One block, 512 threads.
// ---------------------------------------------------------------------------
__global__ __launch_bounds__(512) void k_ue(
    const float* __restrict__ W1, const float* __restrict__ W2,
    const float* __restrict__ W3, const float* __restrict__ Wv,
    float* __restrict__ ue) {
  __shared__ float wv[H], t1[H], t2[H];
  const int tid = threadIdx.x;
  wv[tid] = Wv[tid];
  __syncthreads();
  {
    const float4* row = (const float4*)(W3 + (size_t)tid * H);
    float a = 0.f;
#pragma unroll 4
    for (int j = 0; j < H / 4; ++j) {
      float4 w = row[j];
      a += w.x * wv[4 * j] + w.y * wv[4 * j + 1] + w.z * wv[4 * j + 2] + w.w * wv[4 * j + 3];
    }
    t1[tid] = a;
  }
  __syncthreads();
  {
    const float4* row = (const float4*)(W2 + (size_t)tid * H);
    float a = 0.f;
#pragma unroll 4
    for (int j = 0; j < H / 4; ++j) {
      float4 w = row[j];
      a += w.x * t1[4 * j] + w.y * t1[4 * j + 1] + w.z * t1[4 * j + 2] + w.w * t1[4 * j + 3];
    }
    t2[tid] = a;
  }
  __syncthreads();
  {
    const float4* row = (const float4*)(W1 + (size_t)tid * H);  // rows 0..511 = enc part
    float a = 0.f;
#pragma unroll 4
    for (int j = 0; j < H / 4; ++j) {
      float4 w = row[j];
      a += w.x * t2[4 * j] + w.y * t2[4 * j + 1] + w.z * t2[4 * j + 2] + w.w * t2[4 * j + 3];
    }
    ue[tid] = a;
  }
}

// ---------------------------------------------------------------------------
// Kernel B: per batch b: score[s] = enc[b,s,:]·u_e ; aw = softmax_s(score);
// ctx[b,:] = sum_s aw[s]*enc[b,s,:].  Time-invariant. 64 blocks x 256 threads.
// ---------------------------------------------------------------------------
__global__ __launch_bounds__(256) void k_attn(
    const float* __restrict__ enc, const float* __restrict__ ue,
    float* __restrict__ ctx) {
  __shared__ float uel[H];
  __shared__ float sc[NS];
  __shared__ float red[NS];
  const int b = blockIdx.x;
  const int tid = threadIdx.x;
  uel[tid] = ue[tid];
  uel[tid + 256] = ue[tid + 256];
  __syncthreads();
  float acc = 0.f;
  {
    const float4* row = (const float4*)(enc + ((size_t)b * NS + tid) * H);
#pragma unroll 4
    for (int j = 0; j < H / 4; ++j) {
      float4 e = row[j];
      acc += e.x * uel[4 * j] + e.y * uel[4 * j + 1] + e.z * uel[4 * j + 2] + e.w * uel[4 * j + 3];
    }
  }
  red[tid] = acc;
  __syncthreads();
  for (int s = 128; s > 0; s >>= 1) {
    if (tid < s) red[tid] = fmaxf(red[tid], red[tid + s]);
    __syncthreads();
  }
  const float mx = red[0];
  __syncthreads();
  const float ex = expf(acc - mx);
  red[tid] = ex;
  __syncthreads();
  for (int s = 128; s > 0; s >>= 1) {
    if (tid < s) red[tid] += red[tid + s];
    __syncthreads();
  }
  const float inv = 1.f / red[0];
  sc[tid] = ex * inv;
  __syncthreads();
  for (int h0 = 0; h0 < H; h0 += 256) {
    const int hh = h0 + tid;
    float a = 0.f;
    for (int s = 0; s < NS; ++s) a += sc[s] * enc[((size_t)b * NS + s) * H + hh];
    ctx[b * H + hh] = a;
  }
}

// ---------------------------------------------------------------------------
// Kernel B2: gctx[b,k] = bih[k]+bhh[k] + sum_j ctx[b,j]*Wih[WD+j, k]
// (time-invariant part of the LSTM pre-activation). 64 blocks x 256 threads.
// ---------------------------------------------------------------------------
__global__ __launch_bounds__(256) void k_gctx(
    const float* __restrict__ Wih, const float* __restrict__ bih,
    const float* __restrict__ bhh, const float* __restrict__ ctx,
    float* __restrict__ gctx) {
  __shared__ float cl[8 * H];
  const int tid = threadIdx.x;
  const int kx = blockIdx.x & 7, bg = blockIdx.x >> 3;
  const int k = kx * 256 + tid;
  for (int i = tid; i < 8 * H; i += 256) cl[i] = ctx[(size_t)bg * 8 * H + i];
  __syncthreads();
  float acc[8];
  const float bias = bih[k] + bhh[k];
#pragma unroll
  for (int r = 0; r < 8; ++r) acc[r] = bias;
  const float* wp = Wih + (size_t)WD * G4 + k;
  for (int j = 0; j < H; ++j) {
    float w = wp[(size_t)j * G4];
#pragma unroll
    for (int r = 0; r < 8; ++r) acc[r] += cl[r * H + j] * w;
  }
#pragma unroll
  for (int r = 0; r < 8; ++r) gctx[(size_t)(bg * 8 + r) * G4 + k] = acc[r];
}

// ---------------------------------------------------------------------------
// Kernel W-conv (once): split Wout fp32 [512][30000] into bf16 hi/lo stored in
// MFMA-B-fragment-major layout. frag = vt*16+kt; lane l of a frag holds
// B[k = kt*32 + (l>>4)*8 + e][v = vt*16 + (l&15)], e=0..7, stored contiguously
// at (frag*64 + lane)*8. Grid: 1.92M threads = 7500 x 256.
// ---------------------------------------------------------------------------
__global__ __launch_bounds__(256) void k_convW(
    const float* __restrict__ Wout, unsigned short* __restrict__ whi,
    unsigned short* __restrict__ wlo) {
  const int gid = blockIdx.x * 256 + threadIdx.x;   // 0 .. 1,920,000-1
  const int frag = gid >> 6, lane = gid & 63;
  const int vt = frag >> 4, kt = frag & 15;
  const int v  = vt * 16 + (lane & 15);
  const int k0 = kt * 32 + (lane >> 4) * 8;
  u16x8 hv, lv;
#pragma unroll
  for (int e = 0; e < 8; ++e) {
    float x = Wout[(size_t)(k0 + e) * NV + v];
    unsigned short hb = bf16rne(x);
    float hf = __uint_as_float((unsigned)hb << 16);
    hv[e] = hb;
    lv[e] = bf16rne(x - hf);
  }
  *(u16x8*)(whi + (size_t)gid * 8) = hv;
  *(u16x8*)(wlo + (size_t)gid * 8) = lv;
}

// ---------------------------------------------------------------------------
// Kernel W2-conv (once): split the stacked gate weight [Wih_top(1024); Whh(512)]
// fp32 [1536][2048] into bf16 hi/lo fragment-major. frag = vt*48 + kt
// (vt = 0..127, kt = 0..47); lane l holds W[k = kt*32+(l>>4)*8+e][n = vt*16+(l&15)].
// Grid: 128*48*64 = 393216 threads = 1536 x 256.
// ---------------------------------------------------------------------------
__global__ __launch_bounds__(256) void k_convW2(
    const float* __restrict__ Wih, const float* __restrict__ Whh,
    unsigned short* __restrict__ whi2, unsigned short* __restrict__ wlo2) {
  const int gid = blockIdx.x * 256 + threadIdx.x;
  const int frag = gid >> 6, lane = gid & 63;
  const int vt = frag / NKT, kt = frag % NKT;
  const int n  = vt * 16 + (lane & 15);
  const int k0 = kt * 32 + (lane >> 4) * 8;
  u16x8 hv, lv;
#pragma unroll
  for (int e = 0; e < 8; ++e) {
    int k = k0 + e;
    float x = (k < WD) ? Wih[(size_t)k * G4 + n] : Whh[(size_t)(k - WD) * G4 + n];
    unsigned short hb = bf16rne(x);
    float hf = __uint_as_float((unsigned)hb << 16);
    hv[e] = hb;
    lv[e] = bf16rne(x - hf);
  }
  *(u16x8*)(whi2 + (size_t)gid * 8) = hv;
  *(u16x8*)(wlo2 + (size_t)gid * 8) = lv;
}

// ---------------------------------------------------------------------------
// Kernel H0 (once): convert h0 = encLast into the h fragment buffer hf0
// ([mt][16][64][8] bf16 hi/lo). 64 blocks x 64 threads.
// ---------------------------------------------------------------------------
__global__ __launch_bounds__(64) void k_h0(
    const float* __restrict__ encLast,
    unsigned short* __restrict__ h0hi, unsigned short* __restrict__ h0lo) {
  const int b = blockIdx.x, tid = threadIdx.x;
  const int mt = b >> 4;
  const int lane = (b & 15) | ((tid & 3) << 4);
  const float* src = encLast + (size_t)b * H + tid * 8;
  bf16x8 hv, lv;
  split8(*(const float4*)src, *(const float4*)(src + 4), hv, lv);
  const size_t fi = ((size_t)(mt * 16 + (tid >> 2)) * 64 + lane) * 8;
  *(bf16x8*)(h0hi + fi) = hv;
  *(bf16x8*)(h0lo + fi) = lv;
}

// ---------------------------------------------------------------------------
// Kernel C (per step): gates = [emb[ciw]; h] @ [Wih_top;Whh] via split-bf16
// MFMA + gctx, fused LSTM pointwise + h fragment emission (double-buffered).
// Emb rows are gathered + split in-wave (no separate k_emb). Grid dim3(32,2):
// x = h-col group (16 cols), p = mt-pair (32 batches). 512 threads = 8 waves:
// wave w = gate (w&3), K-half (w>>2) of the 48 k-tiles; halves summed in LDS.
// Block (0,0) also writes pred(t-1) and zeroes packedCur.
// ---------------------------------------------------------------------------
__global__ __launch_bounds__(512) void k_gates(
    const unsigned short* __restrict__ whi2, const unsigned short* __restrict__ wlo2,
    const float* __restrict__ emb,
    const unsigned short* __restrict__ hihi, const unsigned short* __restrict__ hilo,
    unsigned short* __restrict__ hohi, unsigned short* __restrict__ holo,
    const unsigned long long* __restrict__ packedPrev,
    unsigned long long* __restrict__ packedCur,
    float* __restrict__ pred,
    const float* __restrict__ gctx, float* __restrict__ cbuf, int step) {
  __shared__ float gl[8][32][17];   // [wave][b_local][col] padded
  __shared__ int ciws[32];
  const int tid = threadIdx.x;
  const int lane = tid & 63, w = tid >> 6;
  const int g = w & 3, kh = w >> 2;
  const int x = blockIdx.x, p = blockIdx.y;
  const int vt = g * 32 + x;

  if (tid < 32) {
    int b = p * 32 + tid;
    int ciw = 1;  // <BOS>
    if (step > 0) {
      unsigned long long kp = packedPrev[b * PSTR];
      ciw = 0x7FFFFFFF - (int)(unsigned)(kp & 0xFFFFFFFFull);
    }
    ciws[tid] = ciw;
  }
  if (x == 0 && p == 0 && tid < NB) {
    if (step > 0) {
      unsigned long long kp = packedPrev[tid * PSTR];
      int v = 0x7FFFFFFF - (int)(unsigned)(kp & 0xFFFFFFFFull);
      pred[tid * NSTEP + (step - 1)] = (float)v;
    }
    packedCur[tid * PSTR] = 0ull;   // zeroed before k_logits (stream-ordered)
  }
  __syncthreads();

  const float* rb0 = emb + (size_t)ciws[lane & 15] * WD;
  const float* rb1 = emb + (size_t)ciws[16 + (lane & 15)] * WD;
  const int koff = (lane >> 4) * 8;

  f32x4 acc0 = {0.f, 0.f, 0.f, 0.f};
  f32x4 acc1 = {0.f, 0.f, 0.f, 0.f};
  const bf16x8* wh = (const bf16x8*)whi2 + (size_t)vt * NKT * 64 + lane;
  const bf16x8* wl = (const bf16x8*)wlo2 + (size_t)vt * NKT * 64 + lane;
  const bf16x8* ahh = (const bf16x8*)hihi + (size_t)(p * 2) * 16 * 64 + lane;
  const bf16x8* ahl = (const bf16x8*)hilo + (size_t)(p * 2) * 16 * 64 + lane;

  const int kt0 = kh * 24;
#pragma unroll 2
  for (int kt = kt0; kt < kt0 + 24; ++kt) {
    bf16x8 bh = wh[kt * 64];
    bf16x8 bl = wl[kt * 64];
    bf16x8 a0h, a0l, a1h, a1l;
    if (kt < 32) {      // emb part (wave-uniform branch)
      const float* s0 = rb0 + kt * 32 + koff;
      const float* s1 = rb1 + kt * 32 + koff;
      split8(*(const float4*)s0, *(const float4*)(s0 + 4), a0h, a0l);
      split8(*(const float4*)s1, *(const float4*)(s1 + 4), a1h, a1l);
    } else {            // h part (preconverted fragments)
      const int ht = kt - 32;
      a0h = ahh[ht * 64];        a0l = ahl[ht * 64];
      a1h = ahh[(16 + ht) * 64]; a1l = ahl[(16 + ht) * 64];
    }
    acc0 = __builtin_amdgcn_mfma_f32_16x16x32_bf16(a0h, bh, acc0, 0, 0, 0);
    acc0 = __builtin_amdgcn_mfma_f32_16x16x32_bf16(a0l, bh, acc0, 0, 0, 0);
    acc0 = __builtin_amdgcn_mfma_f32_16x16x32_bf16(a0h, bl, acc0, 0, 0, 0);
    acc1 = __builtin_amdgcn_mfma_f32_16x16x32_bf16(a1h, bh, acc1, 0, 0, 0);
    acc1 = __builtin_amdgcn_mfma_f32_16x16x32_bf16(a1l, bh, acc1, 0, 0, 0);
    acc1 = __builtin_amdgcn_mfma_f32_16x16x32_bf16(a1h, bl, acc1, 0, 0, 0);
  }
  {
    const int c = lane & 15, rbase = (lane >> 4) * 4;
#pragma unroll
    for (int r = 0; r < 4; ++r) {
      gl[w][rbase + r][c] = acc0[r];
      gl[w][16 + rbase + r][c] = acc1[r];
    }
  }
  __syncthreads();
  // pointwise LSTM: 512 (b,i) pairs, one per thread; K-halves summed here
  {
    const int bl_ = tid >> 4, c = tid & 15;
    const int b = p * 32 + bl_;
    const int i = x * 16 + c;
    const float* gb = gctx + (size_t)b * G4 + i;
    float gi = gl[0][bl_][c] + gl[4][bl_][c] + gb[0];
    float gf = gl[1][bl_][c] + gl[5][bl_][c] + gb[512];
    float gg = gl[2][bl_][c] + gl[6][bl_][c] + gb[1024];
    float go = gl[3][bl_][c] + gl[7][bl_][c] + gb[1536];
    float cp = (step == 0) ? 0.f : cbuf[b * H + i];
    float si = 1.f / (1.f + expf(-gi));
    float sf = 1.f / (1.f + expf(-gf));
    float so = 1.f / (1.f + expf(-go));
    float cn = sf * cp + si * tanhf(gg);
    float hn = so * tanhf(cn);
    cbuf[b * H + i] = cn;
    // emit bf16 hi/lo fragment element of new h into the OUT buffer
    unsigned short hb = bf16rne(hn);
    float hf = __uint_as_float((unsigned)hb << 16);
    unsigned short lb = bf16rne(hn - hf);
    const int mt = b >> 4;
    const int kt2 = i >> 5;
    const int lane2 = (b & 15) | (((i >> 3) & 3) << 4);
    const int e2 = i & 7;
    const size_t fi = ((size_t)(mt * 16 + kt2) * 64 + lane2) * 8 + e2;
    hohi[fi] = hb;
    holo[fi] = lb;
  }
}

// ---------------------------------------------------------------------------
// Kernel D (per step): logits = h @ Wout + bout via split-bf16 MFMA.
// v2: no A preload (A streamed from L2-hot h buffer), each wave processes a
// PAIR of v-tiles (2x memory-level parallelism, A loads amortized), grid
// doubled to 938 blocks, VGPR capped for 4 waves/EU occupancy.
// ---------------------------------------------------------------------------
__global__ __launch_bounds__(256, 4) void k_logits_mfma(
    const unsigned short* __restrict__ whi, const unsigned short* __restrict__ wlo,
    const unsigned short* __restrict__ hfhi, const unsigned short* __restrict__ hflo,
    const float* __restrict__ bout, float* __restrict__ outSeq,
    unsigned long long* __restrict__ packedCur, int step) {
  const int tid  = threadIdx.x;
  const int lane = tid & 63;
  const int mt   = tid >> 6;            // wave id = m-tile (16 batches)
  const int vtA  = blockIdx.x * 2;
  const bool vbok = (vtA + 1) < NVT;
  const int vtB  = vbok ? vtA + 1 : vtA;
  const int vlane = lane & 15, rgrp = lane >> 4;

  const bf16x8* hh  = (const bf16x8*)hfhi + (size_t)mt * 16 * 64 + lane;
  const bf16x8* hl  = (const bf16x8*)hflo + (size_t)mt * 16 * 64 + lane;
  const bf16x8* whA = (const bf16x8*)whi + (size_t)vtA * 16 * 64 + lane;
  const bf16x8* wlA = (const bf16x8*)wlo + (size_t)vtA * 16 * 64 + lane;
  const bf16x8* whB = (const bf16x8*)whi + (size_t)vtB * 16 * 64 + lane;
  const bf16x8* wlB = (const bf16x8*)wlo + (size_t)vtB * 16 * 64 + lane;

  f32x4 accA = {0.f, 0.f, 0.f, 0.f};
  f32x4 accB = {0.f, 0.f, 0.f, 0.f};
#pragma unroll 2
  for (int kt = 0; kt < 16; ++kt) {
    bf16x8 ah = hh[kt * 64];
    bf16x8 al = hl[kt * 64];
    bf16x8 bhA = whA[kt * 64];
    bf16x8 blA = wlA[kt * 64];
    bf16x8 bhB = whB[kt * 64];
    bf16x8 blB = wlB[kt * 64];
    accA = __builtin_amdgcn_mfma_f32_16x16x32_bf16(ah, bhA, accA, 0, 0, 0);
    accA = __builtin_amdgcn_mfma_f32_16x16x32_bf16(al, bhA, accA, 0, 0, 0);
    accA = __builtin_amdgcn_mfma_f32_16x16x32_bf16(ah, blA, accA, 0, 0, 0);
    accB = __builtin_amdgcn_mfma_f32_16x16x32_bf16(ah, bhB, accB, 0, 0, 0);
    accB = __builtin_amdgcn_mfma_f32_16x16x32_bf16(al, bhB, accB, 0, 0, 0);
    accB = __builtin_amdgcn_mfma_f32_16x16x32_bf16(ah, blB, accB, 0, 0, 0);
  }

  unsigned long long bestk[4] = {0ull, 0ull, 0ull, 0ull};
  const int bbase = mt * 16 + rgrp * 4;
  {
    const int v = vtA * 16 + vlane;
    const float bo = bout[v];
    float* op = outSeq + ((size_t)bbase * NSTEP + step) * NV + v;
#pragma unroll
    for (int r = 0; r < 4; ++r) {
      float val = accA[r] + bo;
      op[(size_t)r * NSTEP * NV] = val;
      unsigned long long key = ((unsigned long long)fkey(val) << 32)
                             | (unsigned long long)(0x7FFFFFFFu - (unsigned)v);
      if (key > bestk[r]) bestk[r] = key;
    }
  }
  if (vbok) {
    const int v = vtB * 16 + vlane;
    const float bo = bout[v];
    float* op = outSeq + ((size_t)bbase * NSTEP + step) * NV + v;
#pragma unroll
    for (int r = 0; r < 4; ++r) {
      float val = accB[r] + bo;
      op[(size_t)r * NSTEP * NV] = val;
      unsigned long long key = ((unsigned long long)fkey(val) << 32)
                             | (unsigned long long)(0x7FFFFFFFu - (unsigned)v);
      if (key > bestk[r]) bestk[r] = key;
    }
  }

  // reduce over the 16 v-lanes (xor masks <16 stay within the rgrp group)
#pragma unroll
  for (int m = 8; m >= 1; m >>= 1) {
#pragma unroll
    for (int r = 0; r < 4; ++r) {
      unsigned long long o = __shfl_xor(bestk[r], m, 64);
      if (o > bestk[r]) bestk[r] = o;
    }
  }
  if (vlane == 0) {
#pragma unroll
    for (int r = 0; r < 4; ++r)
      atomicMax(&packedCur[(bbase + r) * PSTR], bestk[r]);
  }
}

// Final prediction (step 26) from last packed argmax.
__global__ void k_predfinal(const unsigned long long* __restrict__ packed,
                            float* __restrict__ pred) {
  const int b = threadIdx.x;
  int v = 0x7FFFFFFF - (int)(unsigned)(packed[b * PSTR] & 0xFFFFFFFFull);
  pred[b * NSTEP + (NSTEP - 1)] = (float)v;
}

// ---------------------------------------------------------------------------
extern "C" void kernel_launch(void* const* d_in, const int* in_sizes, int n_in,
                              void* d_out, int out_size, void* d_ws, size_t ws_size,
                              hipStream_t stream) {
  (void)in_sizes; (void)n_in; (void)out_size; (void)ws_size;
  const float* encLast = (const float*)d_in[0];   // (1,B,H)
  const float* enc     = (const float*)d_in[1];   // (B,S,H)
  const float* emb     = (const float*)d_in[4];   // (V,WD)
  const float* W1      = (const float*)d_in[5];
  const float* W2      = (const float*)d_in[7];
  const float* W3      = (const float*)d_in[9];
  const float* Wv      = (const float*)d_in[11];
  const float* Wih     = (const float*)d_in[12];  // (1536,2048)
  const float* Whh     = (const float*)d_in[13];  // (512,2048)
  const float* bih     = (const float*)d_in[14];
  const float* bhh     = (const float*)d_in[15];
  const float* Wout    = (const float*)d_in[16];  // (512,30000)
  const float* bout    = (const float*)d_in[17];
  // b1/b2/b3 (d_in[6,8,10]) cancel in softmax; targets/tr_steps unused.

  // Workspace layout (float-unit offsets; non-overlapping, total ~75.3 MB):
  float* wsf = (float*)d_ws;
  float* ue   = wsf;                 // +512      -> 512
  float* ctx  = wsf + 512;           // +32768    -> 33280
  float* gctx = wsf + 33280;         // +131072   -> 164352
  float* cbuf = wsf + 164352;        // +32768    -> 197120
  unsigned long long* packedP = (unsigned long long*)(wsf + 197120); // 27*64*16 u64 = +55296 -> 252416
  unsigned short* h0hi = (unsigned short*)(wsf + 252416);   // 32768 u16 = +16384 -> 268800
  unsigned short* h0lo = (unsigned short*)(wsf + 268800);   // +16384 -> 285184
  unsigned short* h1hi = (unsigned short*)(wsf + 285184);   // +16384 -> 301568
  unsigned short* h1lo = (unsigned short*)(wsf + 301568);   // +16384 -> 317952
  unsigned short* whi2 = (unsigned short*)(wsf + 317952);   // 3145728 u16 = +1572864 -> 1890816
  unsigned short* wlo2 = (unsigned short*)(wsf + 1890816);  // +1572864 -> 3463680
  unsigned short* whi  = (unsigned short*)(wsf + 3463680);  // 15360000 u16 = +7680000 -> 11143680
  unsigned short* wlo  = (unsigned short*)(wsf + 11143680); // +7680000 -> 18823680

  float* outSeq = (float*)d_out;                        // fp32 seq [B,27,V]
  float* pred   = outSeq + (size_t)NB * NSTEP * NV;     // fp32 preds [B,27]

  k_ue    <<<1, 512, 0, stream>>>(W1, W2, W3, Wv, ue);
  k_attn  <<<NB, 256, 0, stream>>>(enc, ue, ctx);
  k_gctx  <<<64, 256, 0, stream>>>(Wih, bih, bhh, ctx, gctx);
  k_convW <<<7500, 256, 0, stream>>>(Wout, whi, wlo);
  k_convW2<<<1536, 256, 0, stream>>>(Wih, Whh, whi2, wlo2);
  k_h0    <<<NB, 64, 0, stream>>>(encLast, h0hi, h0lo);

  for (int t = 0; t < NSTEP; ++t) {
    const unsigned long long* pprev = packedP + (t > 0 ? (size_t)(t - 1) * NB * PSTR : 0);
    unsigned long long* pcur = packedP + (size_t)t * NB * PSTR;
    // h double-buffer: even steps read hf0 / write hf1; odd steps the reverse.
    const unsigned short* hihi = (t & 1) ? h1hi : h0hi;
    const unsigned short* hilo = (t & 1) ? h1lo : h0lo;
    unsigned short* hohi = (t & 1) ? h0hi : h1hi;
    unsigned short* holo = (t & 1) ? h0lo : h1lo;
    k_gates<<<dim3(32, 2), 512, 0, stream>>>(whi2, wlo2, emb,
                                             hihi, hilo, hohi, holo,
                                             pprev, pcur, pred,
                                             gctx, cbuf, t);
    k_logits_mfma<<<938, 256, 0, stream>>>(whi, wlo, hohi, holo, bout, outSeq,
                                           pcur, t);
  }
  k_predfinal<<<1, NB, 0, stream>>>(packedP + (size_t)(NSTEP - 1) * NB * PSTR, pred);
}